// Round 15
// baseline (34.369 us; speedup 1.0000x reference)
//
#include <hip/hip_runtime.h>

#define NB 32
#define NT 2048
#define TOUT 512
#define ND 256
#define BLK_J 32
#define LDA 264   // ushort stride for pooled rows: 528B, 16B-aligned for ds_read_b128

typedef __attribute__((ext_vector_type(4))) float f32x4;
typedef __attribute__((ext_vector_type(8))) short bf16x8;
typedef __attribute__((ext_vector_type(4))) unsigned short u16x4;

__device__ __forceinline__ unsigned short f2b(float f) {
    unsigned int u = __builtin_bit_cast(unsigned int, f);
    return (unsigned short)((u + 0x7FFFu + ((u >> 16) & 1u)) >> 16);  // RNE
}

// tanh-form GELU as sigmoid; max dev from exact ~3e-4 << 0.14 budget (R10-R14 passed).
__device__ __forceinline__ float gelu_fast(float x) {
    float x2 = x * x;
    float p  = x * fmaf(x2, 0.044715f, 1.0f);
    float a  = fminf(1.5957691216f * p, 80.0f);
    float e  = __expf(a);
    return x * __fdividef(e, e + 1.0f);
}

template <int K>
__device__ __forceinline__ f32x4 sumK(const float* p) {
    f32x4 v[K];
    #pragma unroll
    for (int t = 0; t < K; ++t)
        v[t] = *reinterpret_cast<const f32x4*>(p + (size_t)t * ND);
    f32x4 s = v[0];
    #pragma unroll
    for (int t = 1; t < K; ++t) s += v[t];
    return s;
}

// SINGLE-LAUNCH fused kernel. Grid (32,16) x 512 thr, 1 block/CU (LDS-limited).
// Phase A: pool 32 rows (4/wave) -> a_lds  ||  stage W f32 -> bf16 fragment-major w_lds.
// Phase B (x2 tiles): MFMA (A from a_lds, B from w_lds) -> GELU in regs ->
//   in-register LN (shfl row-reduce + 1KB cross-wave scratch) -> direct store.
// No cvt kernel, no workspace, no h_lds. 3 barriers total.
__global__ __launch_bounds__(512, 2)
void fused_one(const float* __restrict__ mu,
               const int* __restrict__ lens,
               const int* __restrict__ olens,
               const float* __restrict__ wf,
               const float* __restrict__ gamma,
               const float* __restrict__ beta,
               float* __restrict__ out)
{
    __shared__ unsigned short w_lds[16 * 8 * 64 * 8];  // 128 KB fragment-major W
    __shared__ unsigned short a_lds[2][16 * LDA];      // 16.5 KB pooled rows (2 tiles)
    __shared__ float red_s[2][8][16];                  // 1 KB row-sum partials
    __shared__ float red_q[2][8][16];                  // 1 KB row-sqsum partials

    const int b    = blockIdx.x;
    const int j0   = blockIdx.y * BLK_J;
    const int tid  = (int)threadIdx.x;
    const int lane = tid & 63;
    const int wv   = tid >> 6;     // 0..7, e-range [wv*32, wv*32+32)
    const int r    = lane & 15;
    const int kg   = lane >> 4;

    const int L = lens[b];
    const int O = olens[b];

    // ---- Phase A1: ragged pool, 4 rows/wave (32 rows), exact-count loads ----
    #pragma unroll
    for (int i = 0; i < 4; ++i) {
        const int m = wv + i * 8;          // 0..31
        const int j = j0 + m;
        f32x4 s = {0.f, 0.f, 0.f, 0.f};
        if (j < O) {
            const int st  = (j * L) / O;
            const int en  = ((j + 1) * L + O - 1) / O;
            const int cnt = en - st;                 // wave-uniform, in [2, 9]
            const float* p = mu + (size_t)(b * NT + st) * ND + lane * 4;
            switch (cnt) {                           // uniform scalar branch
                case 2: s = sumK<2>(p); break;
                case 3: s = sumK<3>(p); break;
                case 4: s = sumK<4>(p); break;
                case 5: s = sumK<5>(p); break;
                case 6: s = sumK<6>(p); break;
                case 7: s = sumK<7>(p); break;
                case 8: s = sumK<8>(p); break;
                case 9: s = sumK<9>(p); break;
                default:
                    for (int t = 0; t < cnt; ++t)
                        s += *reinterpret_cast<const f32x4*>(p + (size_t)t * ND);
                    break;
            }
            s *= 1.0f / (float)cnt;
        }
        u16x4 q;
        q.x = f2b(s.x); q.y = f2b(s.y); q.z = f2b(s.z); q.w = f2b(s.w);
        *reinterpret_cast<u16x4*>(&a_lds[m >> 4][(m & 15) * LDA + lane * 4]) = q;
    }

    // ---- Phase A2: W f32 -> bf16 fragment-major in LDS (coalesced global reads)
    //      w_lds[((et*8+kk)*64 + kg*16+r)*8 + i] = W[et*16+r][kk*32+kg*8+i]
    #pragma unroll
    for (int it = 0; it < 32; ++it) {
        const int gid = it * 512 + tid;            // f32x4 chunk index, 16384 total
        const int e   = gid >> 6;                  // W row 0..255
        const int k   = (gid & 63) * 4;            // col 0..252 step 4
        f32x4 w4 = *reinterpret_cast<const f32x4*>(wf + (size_t)e * ND + k);
        const int et  = e >> 4, rr = e & 15;
        const int kk  = k >> 5, kgg = (k >> 3) & 3, i0 = k & 7;   // i0 in {0,4}
        const int dst = (((et * 8 + kk) * 64) + (kgg * 16 + rr)) * 8 + i0;
        u16x4 pk;
        pk.x = f2b(w4.x); pk.y = f2b(w4.y); pk.z = f2b(w4.z); pk.w = f2b(w4.w);
        *reinterpret_cast<u16x4*>(&w_lds[dst]) = pk;
    }
    __syncthreads();

    // ---- gamma/beta for this thread's two columns ----
    const int col0 = wv * 32 + r;        // p = 0
    const int col1 = col0 + 16;          // p = 1
    const float g0 = gamma[col0], g1 = gamma[col1];
    const float be0 = beta[col0], be1 = beta[col1];

    // ---- Phase B: two 16-row tiles ----
    #pragma unroll
    for (int t = 0; t < 2; ++t) {
        f32x4 acc[2];
        acc[0] = (f32x4){0.f, 0.f, 0.f, 0.f};
        acc[1] = (f32x4){0.f, 0.f, 0.f, 0.f};
        #pragma unroll
        for (int kk = 0; kk < 8; ++kk) {
            const int k0 = kk * 32 + kg * 8;
            bf16x8 af = *reinterpret_cast<const bf16x8*>(&a_lds[t][r * LDA + k0]);
            bf16x8 b0 = *reinterpret_cast<const bf16x8*>(
                &w_lds[(((wv * 2 + 0) * 8 + kk) * 64 + lane) * 8]);
            bf16x8 b1 = *reinterpret_cast<const bf16x8*>(
                &w_lds[(((wv * 2 + 1) * 8 + kk) * 64 + lane) * 8]);
            acc[0] = __builtin_amdgcn_mfma_f32_16x16x32_bf16(af, b0, acc[0], 0, 0, 0);
            acc[1] = __builtin_amdgcn_mfma_f32_16x16x32_bf16(af, b1, acc[1], 0, 0, 0);
        }

        // GELU in registers + per-row partial sums.
        // C/D layout (verified m89): row = kg*4+q, col = wv*32 + p*16 + r.
        float gv[2][4], ps[4], pq[4];
        #pragma unroll
        for (int q = 0; q < 4; ++q) { ps[q] = 0.f; pq[q] = 0.f; }
        #pragma unroll
        for (int p = 0; p < 2; ++p)
            #pragma unroll
            for (int q = 0; q < 4; ++q) {
                const float g = gelu_fast(acc[p][q]);
                gv[p][q] = g;
                ps[q] += g;
                pq[q] += g * g;
            }
        // reduce across the 16 r-lanes of this kg-group (offsets touch r-bits only)
        #pragma unroll
        for (int q = 0; q < 4; ++q)
            #pragma unroll
            for (int off = 1; off < 16; off <<= 1) {
                ps[q] += __shfl_xor(ps[q], off, 64);
                pq[q] += __shfl_xor(pq[q], off, 64);
            }
        if (r == 0) {
            #pragma unroll
            for (int q = 0; q < 4; ++q) {
                red_s[t][wv][kg * 4 + q] = ps[q];
                red_q[t][wv][kg * 4 + q] = pq[q];
            }
        }
        __syncthreads();

        // finish LN per row (broadcast LDS reads), store straight from registers
        #pragma unroll
        for (int q = 0; q < 4; ++q) {
            float ts = 0.f, tq = 0.f;
            #pragma unroll
            for (int w2 = 0; w2 < 8; ++w2) {
                ts += red_s[t][w2][kg * 4 + q];
                tq += red_q[t][w2][kg * 4 + q];
            }
            const float mean = ts * (1.0f / 256.0f);
            const float var  = tq * (1.0f / 256.0f) - mean * mean;
            const float rs   = rsqrtf(var + 1e-5f);
            const int row = j0 + t * 16 + kg * 4 + q;
            float* orow = out + (size_t)(b * TOUT + row) * ND;
            orow[col0] = (gv[0][q] - mean) * rs * g0 + be0;
            orow[col1] = (gv[1][q] - mean) * rs * g1 + be1;
        }
        // next tile uses red[t^1] and a_lds[t^1]: no extra barrier needed
    }
}

extern "C" void kernel_launch(void* const* d_in, const int* in_sizes, int n_in,
                              void* d_out, int out_size, void* d_ws, size_t ws_size,
                              hipStream_t stream) {
    const float* mu    = (const float*)d_in[0];
    const int*   lens  = (const int*)d_in[1];
    const int*   olens = (const int*)d_in[2];
    const float* wf    = (const float*)d_in[3];
    const float* gamma = (const float*)d_in[4];
    const float* beta  = (const float*)d_in[5];
    float* out = (float*)d_out;

    fused_one<<<dim3(NB, TOUT / BLK_J), dim3(512), 0, stream>>>(
        mu, lens, olens, wf, gamma, beta, out);
}